// Round 3
// baseline (253.196 us; speedup 1.0000x reference)
//
#include <hip/hip_runtime.h>
#include <cstdint>
#include <cstddef>

#define NTOK 16384
#define FDIM 32
#define HDIM 128
#define TOKB 32

typedef __attribute__((ext_vector_type(8))) short short8;     // bf16x8 MFMA frag
typedef __attribute__((ext_vector_type(4))) float float4v;
typedef __attribute__((ext_vector_type(2))) float float2v;
typedef __attribute__((ext_vector_type(4))) unsigned int uint4v;

__device__ __forceinline__ float elu_f(float x)  { return x > 0.f ? x : __expf(x) - 1.f; }
__device__ __forceinline__ float sigm_f(float x) { return 1.f / (1.f + __expf(-x)); }

// fp32 -> bf16 RNE (k_pw cold path)
__device__ __forceinline__ unsigned int f2bf(float f) {
  unsigned int u = __float_as_uint(f);
  u += 0x7FFFu + ((u >> 16) & 1u);
  return u >> 16;
}
// packed fp32x2 -> bf16x2 in one VALU op (RNE)
__device__ __forceinline__ unsigned int cvtpk(float lo, float hi) {
  unsigned int r;
  asm("v_cvt_pk_bf16_f32 %0, %1, %2" : "=v"(r) : "v"(lo), "v"(hi));
  return r;
}

// DPP-based add: x + lane-permuted(x). VALU-only, no DS pipe.
template<int CTRL>
__device__ __forceinline__ float dpp_add(float x) {
  int t = __builtin_amdgcn_update_dpp(0, __float_as_int(x), CTRL, 0xF, 0xF, true);
  return x + __int_as_float(t);
}
// full 16-lane sum (all 16 lanes of the row get the total)
__device__ __forceinline__ float r16sum(float x) {
  x = dpp_add<0xB1>(x);    // quad_perm xor1
  x = dpp_add<0x4E>(x);    // quad_perm xor2
  x = dpp_add<0x124>(x);   // row_ror:4
  x = dpp_add<0x128>(x);   // row_ror:8
  return x;
}

// ---------------------------------------------------------------------------
// Kernel 1 (unchanged): fcomb precompute + weight-GRN/softmax.
// ---------------------------------------------------------------------------
__global__ __launch_bounds__(256) void k_pw(
    const float* __restrict__ x,
    const float* __restrict__ fw2, const float* __restrict__ fb2,
    const float* __restrict__ fglu_w, const float* __restrict__ fglu_b,
    const float* __restrict__ ww1, const float* __restrict__ wb1,
    const float* __restrict__ ww2, const float* __restrict__ wb2,
    const float* __restrict__ wglu_w, const float* __restrict__ wglu_b,
    const float* __restrict__ wln_g, const float* __restrict__ wln_b,
    unsigned short* __restrict__ bfrag, float* __restrict__ bcomb,
    float* __restrict__ wout)
{
  __shared__ __align__(16) float smem[4096];
  const int tid = threadIdx.x;

  if (blockIdx.x < 128) {
    const int f  = blockIdx.x >> 2;
    const int ks = blockIdx.x & 3;
    const float* src = fw2 + ((size_t)f * 128 + ks * 32) * 128;
    for (int i = 0; i < 4; ++i) {
      int vi = tid + i * 256;
      *(float4v*)&smem[vi * 4] = *(const float4v*)&src[vi * 4];
    }
    __syncthreads();

    const int o2 = tid;
    float acc[32];
#pragma unroll
    for (int kk = 0; kk < 32; ++kk) acc[kk] = 0.f;
    float bacc = 0.f;

    for (int o = 0; o < 128; o += 4) {
      float gv0 = fglu_w[((size_t)f * 128 + o + 0) * 256 + o2];
      float gv1 = fglu_w[((size_t)f * 128 + o + 1) * 256 + o2];
      float gv2 = fglu_w[((size_t)f * 128 + o + 2) * 256 + o2];
      float gv3 = fglu_w[((size_t)f * 128 + o + 3) * 256 + o2];
      bacc += fb2[f * 128 + o + 0] * gv0 + fb2[f * 128 + o + 1] * gv1
            + fb2[f * 128 + o + 2] * gv2 + fb2[f * 128 + o + 3] * gv3;
#pragma unroll
      for (int kk = 0; kk < 32; ++kk) {
        float4v a4 = *(const float4v*)&smem[kk * 128 + o];
        acc[kk] += a4[0] * gv0 + a4[1] * gv1 + a4[2] * gv2 + a4[3] * gv3;
      }
    }

    const int type = o2 >> 7;
    const int hq   = o2 & 127;
    const int wv   = hq >> 5;
    const int hp   = (hq >> 4) & 1;
    const int cc   = hq & 15;
    const int ct   = wv * 4 + hp * 2 + type;

#pragma unroll
    for (int gg = 0; gg < 4; ++gg) {
      uint4v pk;
      unsigned int u0 = f2bf(acc[gg * 8 + 0]), u1 = f2bf(acc[gg * 8 + 1]);
      unsigned int u2 = f2bf(acc[gg * 8 + 2]), u3 = f2bf(acc[gg * 8 + 3]);
      unsigned int u4 = f2bf(acc[gg * 8 + 4]), u5 = f2bf(acc[gg * 8 + 5]);
      unsigned int u6 = f2bf(acc[gg * 8 + 6]), u7 = f2bf(acc[gg * 8 + 7]);
      pk[0] = u0 | (u1 << 16);
      pk[1] = u2 | (u3 << 16);
      pk[2] = u4 | (u5 << 16);
      pk[3] = u6 | (u7 << 16);
      size_t off = ((((size_t)f * 16 + ct) * 4 + ks) * 64 + (gg * 16 + cc)) * 8;
      *(uint4v*)(bfrag + off) = pk;
    }
    if (ks == 0)
      bcomb[f * 256 + ct * 16 + cc] = bacc + fglu_b[f * 256 + o2];

  } else {
    const int bid = blockIdx.x - 128;
    const int wv  = tid >> 6;
    const int l   = tid & 63;
    const int t   = bid * 4 + wv;
    float* S = smem + wv * 256;

    float xv = x[(size_t)t * 32 + (l & 31)];
    if (l < 32) S[l] = xv;
    float a0 = wb1[l], a1 = wb1[l + 64];
    __syncthreads();
    for (int f2 = 0; f2 < 32; ++f2) {
      float xf = S[f2];
      a0 = fmaf(xf, ww1[f2 * 128 + l], a0);
      a1 = fmaf(xf, ww1[f2 * 128 + l + 64], a1);
    }
    a0 = elu_f(a0); a1 = elu_f(a1);
    S[32 + l] = a0; S[32 + l + 64] = a1;
    __syncthreads();

    const int o    = l & 31;
    const int half = l >> 5;
    float b = 0.f;
    for (int hh = 0; hh < 64; ++hh)
      b = fmaf(S[32 + half * 64 + hh], ww2[(half * 64 + hh) * 32 + o], b);
    b += __shfl_xor(b, 32);
    b += wb2[o];
    S[160 + o] = b;
    __syncthreads();

    float g = wglu_b[l];
    for (int o2i = 0; o2i < 32; ++o2i)
      g = fmaf(S[160 + o2i], wglu_w[o2i * 64 + l], g);

    float gate = __shfl_xor(g, 32);
    float y = g * sigm_f(gate) + xv;
    float s = y;
    s += __shfl_xor(s, 1); s += __shfl_xor(s, 2); s += __shfl_xor(s, 4);
    s += __shfl_xor(s, 8); s += __shfl_xor(s, 16);
    float mean = s * (1.f / 32.f);
    float d = y - mean;
    float ss = d * d;
    ss += __shfl_xor(ss, 1); ss += __shfl_xor(ss, 2); ss += __shfl_xor(ss, 4);
    ss += __shfl_xor(ss, 8); ss += __shfl_xor(ss, 16);
    float rstd = rsqrtf(ss * (1.f / 32.f) + 1e-5f);
    const int cc = l & 31;
    float ln = d * rstd * wln_g[cc] + wln_b[cc];
    float mx = ln;
    mx = fmaxf(mx, __shfl_xor(mx, 1));  mx = fmaxf(mx, __shfl_xor(mx, 2));
    mx = fmaxf(mx, __shfl_xor(mx, 4));  mx = fmaxf(mx, __shfl_xor(mx, 8));
    mx = fmaxf(mx, __shfl_xor(mx, 16));
    float e = __expf(ln - mx);
    float se = e;
    se += __shfl_xor(se, 1); se += __shfl_xor(se, 2); se += __shfl_xor(se, 4);
    se += __shfl_xor(se, 8); se += __shfl_xor(se, 16);
    if (l < 32) wout[(size_t)t * 32 + l] = e / se;
  }
}

// ---------------------------------------------------------------------------
// Kernel 2 v3: single barrier per feature.
//  - a_lds double-buffered: iter f reads buf[f&1], stages f+1 into buf[(f+1)&1]
//  - sred quadruple-buffered: zero buf (f+2)&3 pre-barrier (barrier-separated
//    from last readers at I_{f-1} and next atomics at I_{f+2})
//  - B-frags + scalars for f+1 prefetched into named reg sets (bE/bO), manual
//    2x unroll so no reg-to-reg moves and no runtime-indexed arrays
//  - staging pack via v_cvt_pk_bf16_f32; LDS atomics split across lanes c<2
// ---------------------------------------------------------------------------
struct Scal { float bc0, bc1, fsk, lgm, lbt; };

#define STAGE(F, BUF) do {                                                    \
    int st = tid >> 4, sk = (tid & 15) * 8;                                   \
    float xf = x_lds[(F) * TOKB + st];                                        \
    float4v w1a = *(const float4v*)(fw1 + (F) * HDIM + sk);                   \
    float4v w1b = *(const float4v*)(fw1 + (F) * HDIM + sk + 4);               \
    float4v b1a = *(const float4v*)(fb1 + (F) * HDIM + sk);                   \
    float4v b1b = *(const float4v*)(fb1 + (F) * HDIM + sk + 4);               \
    uint4v pk;                                                                \
    pk[0] = cvtpk(elu_f(fmaf(xf, w1a[0], b1a[0])),                            \
                  elu_f(fmaf(xf, w1a[1], b1a[1])));                           \
    pk[1] = cvtpk(elu_f(fmaf(xf, w1a[2], b1a[2])),                            \
                  elu_f(fmaf(xf, w1a[3], b1a[3])));                           \
    pk[2] = cvtpk(elu_f(fmaf(xf, w1b[0], b1b[0])),                            \
                  elu_f(fmaf(xf, w1b[1], b1b[1])));                           \
    pk[3] = cvtpk(elu_f(fmaf(xf, w1b[2], b1b[2])),                            \
                  elu_f(fmaf(xf, w1b[3], b1b[3])));                           \
    int sb = st * 256 + sk * 2;                                               \
    sb ^= (st & 7) << 4;                                                      \
    *(uint4v*)((char*)a_lds[BUF] + sb) = pk;                                  \
  } while (0)

#define LOADB(F, B, S) do {                                                   \
    const unsigned short* bb = bfrag + (size_t)((F) * 16 + ctb) * 2048;       \
    _Pragma("unroll")                                                         \
    for (int ct2 = 0; ct2 < 2; ++ct2)                                         \
      _Pragma("unroll")                                                       \
      for (int ks = 0; ks < 4; ++ks)                                          \
        B[ct2][ks] = *(const short8*)(bb + ct2 * 2048 + ks * 512 + l * 8);    \
    S.bc0 = bcomb[(F) * 256 + ctb * 16 + c];                                  \
    S.bc1 = bcomb[(F) * 256 + (ctb + 1) * 16 + c];                            \
    S.fsk = fskip[(F) * HDIM + hb + c];                                       \
    S.lgm = flng[(F) * HDIM + hb + c];                                        \
    S.lbt = flnb[(F) * HDIM + hb + c];                                        \
  } while (0)

#define BODY(F, BCUR, SCUR, BNXT, SNXT) do {                                  \
    const int cb2 = (F) & 1, cb4 = (F) & 3;                                   \
    float4v acc[2][2];                                                        \
    _Pragma("unroll")                                                         \
    for (int ct2 = 0; ct2 < 2; ++ct2)                                         \
      _Pragma("unroll")                                                       \
      for (int rt = 0; rt < 2; ++rt)                                          \
        acc[ct2][rt] = (float4v){0.f, 0.f, 0.f, 0.f};                         \
    _Pragma("unroll")                                                         \
    for (int ks = 0; ks < 4; ++ks) {                                          \
      short8 afr[2];                                                          \
      _Pragma("unroll")                                                       \
      for (int rt = 0; rt < 2; ++rt) {                                        \
        int row  = rt * 16 + c;                                               \
        int byte = row * 256 + (ks * 32 + g16 * 8) * 2;                       \
        byte ^= (row & 7) << 4;                                               \
        afr[rt] = *(const short8*)((const char*)a_lds[cb2] + byte);           \
      }                                                                       \
      _Pragma("unroll")                                                       \
      for (int ct2 = 0; ct2 < 2; ++ct2)                                       \
        _Pragma("unroll")                                                     \
        for (int rt = 0; rt < 2; ++rt)                                        \
          acc[ct2][rt] = __builtin_amdgcn_mfma_f32_16x16x32_bf16(             \
              afr[rt], BCUR[ct2][ks], acc[ct2][rt], 0, 0, 0);                 \
    }                                                                         \
    if ((F) < FDIM - 1) STAGE((F) + 1, cb2 ^ 1);                              \
    float yv[2][4], sv[2][4], ssv[2][4];                                      \
    _Pragma("unroll")                                                         \
    for (int rt = 0; rt < 2; ++rt) {                                          \
      float4v x4 = *(const float4v*)&x_lds[(F) * TOKB + rt * 16 + g16 * 4];   \
      _Pragma("unroll")                                                       \
      for (int i = 0; i < 4; ++i) {                                           \
        float v0 = acc[0][rt][i] + SCUR.bc0;                                  \
        float g0 = acc[1][rt][i] + SCUR.bc1;                                  \
        float y  = fmaf(x4[i], SCUR.fsk, v0 * sigm_f(g0));                    \
        yv[rt][i]  = y;                                                       \
        sv[rt][i]  = r16sum(y);                                               \
        ssv[rt][i] = r16sum(y * y);                                           \
      }                                                                       \
    }                                                                         \
    if (c < 2) {                                                              \
      _Pragma("unroll")                                                       \
      for (int rt = 0; rt < 2; ++rt)                                          \
        _Pragma("unroll")                                                     \
        for (int i = 0; i < 4; ++i)                                           \
          atomicAdd(&sred[cb4][c][rt * 16 + g16 * 4 + i],                     \
                    c ? ssv[rt][i] : sv[rt][i]);                              \
    }                                                                         \
    if ((F) < FDIM - 1) LOADB((F) + 1, BNXT, SNXT);                           \
    if (tid < 64) sred[((F) + 2) & 3][tid >> 5][tid & 31] = 0.f;              \
    __syncthreads();                                                          \
    _Pragma("unroll")                                                         \
    for (int rt = 0; rt < 2; ++rt) {                                          \
      float4v s4  = *(const float4v*)&sred[cb4][0][rt * 16 + g16 * 4];        \
      float4v ss4 = *(const float4v*)&sred[cb4][1][rt * 16 + g16 * 4];        \
      float4v w4  = *(const float4v*)&w_lds[(F) * TOKB + rt * 16 + g16 * 4];  \
      _Pragma("unroll")                                                       \
      for (int i = 0; i < 4; ++i) {                                           \
        float mean = s4[i] * (1.f / 128.f);                                   \
        float var  = ss4[i] * (1.f / 128.f) - mean * mean;                    \
        float rstd = rsqrtf(var + 1e-5f);                                     \
        float o2 = (yv[rt][i] - mean) * rstd * SCUR.lgm + SCUR.lbt;           \
        out_acc[rt][i] = fmaf(w4[i], o2, out_acc[rt][i]);                     \
      }                                                                       \
    }                                                                         \
  } while (0)

__global__ __launch_bounds__(512, 4) void k_main(
    const float* __restrict__ x,
    const float* __restrict__ fw1, const float* __restrict__ fb1,
    const float* __restrict__ fskip, const float* __restrict__ flng,
    const float* __restrict__ flnb,
    const unsigned short* __restrict__ bfrag, const float* __restrict__ bcomb,
    const float* __restrict__ wts, float* __restrict__ out)
{
  __shared__ __align__(16) unsigned short a_lds[2][TOKB * 128]; // 2x8 KB
  __shared__ __align__(16) float x_lds[FDIM * TOKB];            // [f][t] 4 KB
  __shared__ __align__(16) float w_lds[FDIM * TOKB];            // [f][t] 4 KB
  __shared__ __align__(16) float sred[4][2][TOKB];              // 1 KB

  const int tid = threadIdx.x;
  const int w   = tid >> 6;
  const int l   = tid & 63;
  const int c   = l & 15;
  const int g16 = l >> 4;
  const int t0  = blockIdx.x * TOKB;
  const int hb  = (w >> 1) * 32 + (w & 1) * 16;   // h-col base for this wave
  const int ctb = (w >> 1) * 4 + (w & 1) * 2;     // ct' base (v at +0, gate +1)

  // stage x and weights tiles, transposed to [f][t]; zero all sred buffers
  {
    float2v xv = *(const float2v*)(x   + (size_t)t0 * FDIM + tid * 2);
    float2v wv = *(const float2v*)(wts + (size_t)t0 * FDIM + tid * 2);
#pragma unroll
    for (int e = 0; e < 2; ++e) {
      int flat = tid * 2 + e;
      int tt = flat >> 5, ff = flat & 31;
      x_lds[ff * TOKB + tt] = xv[e];
      w_lds[ff * TOKB + tt] = wv[e];
    }
    if (tid < 256) ((float*)sred)[tid] = 0.f;
  }

  float out_acc[2][4];
#pragma unroll
  for (int rt = 0; rt < 2; ++rt)
#pragma unroll
    for (int i = 0; i < 4; ++i) out_acc[rt][i] = 0.f;

  __syncthreads();          // x_lds/w_lds/sred ready

  short8 bE[2][4], bO[2][4];
  Scal  sSE, sSO;
  STAGE(0, 0);
  LOADB(0, bE, sSE);
  __syncthreads();          // a_lds[0] ready

  for (int f = 0; f < FDIM; f += 2) {
    BODY(f,     bE, sSE, bO, sSO);
    BODY(f + 1, bO, sSO, bE, sSE);
  }

  // ---- store ----
#pragma unroll
  for (int rt = 0; rt < 2; ++rt)
#pragma unroll
    for (int i = 0; i < 4; ++i) {
      int row = t0 + rt * 16 + g16 * 4 + i;
      out[(size_t)row * HDIM + hb + c] = out_acc[rt][i];
    }
}

extern "C" void kernel_launch(void* const* d_in, const int* in_sizes, int n_in,
                              void* d_out, int out_size, void* d_ws, size_t ws_size,
                              hipStream_t stream) {
  const float* x      = (const float*)d_in[0];
  const float* fw1    = (const float*)d_in[1];
  const float* fb1    = (const float*)d_in[2];
  const float* fw2    = (const float*)d_in[3];
  const float* fb2    = (const float*)d_in[4];
  const float* fglu_w = (const float*)d_in[5];
  const float* fglu_b = (const float*)d_in[6];
  const float* fskip  = (const float*)d_in[7];
  const float* fln_g  = (const float*)d_in[8];
  const float* fln_b  = (const float*)d_in[9];
  const float* ww1    = (const float*)d_in[10];
  const float* wb1    = (const float*)d_in[11];
  const float* ww2    = (const float*)d_in[12];
  const float* wb2    = (const float*)d_in[13];
  const float* wglu_w = (const float*)d_in[14];
  const float* wglu_b = (const float*)d_in[15];
  const float* wln_g  = (const float*)d_in[16];
  const float* wln_b  = (const float*)d_in[17];

  float* outp = (float*)d_out;
  float* wout = outp + (size_t)NTOK * HDIM;

  unsigned short* bfrag = (unsigned short*)d_ws;                  // 2 MiB bf16
  float* bcomb = (float*)((char*)d_ws + (size_t)2 * 1024 * 1024); // 32 KiB f32

  k_pw<<<dim3(128 + NTOK / 4), dim3(256), 0, stream>>>(
      x, fw2, fb2, fglu_w, fglu_b, ww1, wb1, ww2, wb2,
      wglu_w, wglu_b, wln_g, wln_b, bfrag, bcomb, wout);
  k_main<<<dim3(NTOK / TOKB), dim3(512), 0, stream>>>(
      x, fw1, fb1, fskip, fln_g, fln_b, bfrag, bcomb, wout, outp);
}

// Round 4
// 191.840 us; speedup vs baseline: 1.3198x; 1.3198x over previous
//
#include <hip/hip_runtime.h>
#include <cstdint>
#include <cstddef>

#define NTOK 16384
#define FDIM 32
#define HDIM 128
#define TOKB 16

typedef __attribute__((ext_vector_type(8))) short short8;     // bf16x8 MFMA frag
typedef __attribute__((ext_vector_type(4))) float float4v;
typedef __attribute__((ext_vector_type(2))) unsigned int uint2v;
typedef __attribute__((ext_vector_type(4))) unsigned int uint4v;

__device__ __forceinline__ float elu_f(float x)  { return x > 0.f ? x : __expf(x) - 1.f; }
__device__ __forceinline__ float sigm_f(float x) { return 1.f / (1.f + __expf(-x)); }

// fp32 -> bf16 RNE (k_pw cold path)
__device__ __forceinline__ unsigned int f2bf(float f) {
  unsigned int u = __float_as_uint(f);
  u += 0x7FFFu + ((u >> 16) & 1u);
  return u >> 16;
}
// packed fp32x2 -> bf16x2 in one VALU op (RNE)
__device__ __forceinline__ unsigned int cvtpk(float lo, float hi) {
  unsigned int r;
  asm("v_cvt_pk_bf16_f32 %0, %1, %2" : "=v"(r) : "v"(lo), "v"(hi));
  return r;
}

// DPP-based add: x + lane-permuted(x). VALU-only, no DS pipe.
template<int CTRL>
__device__ __forceinline__ float dpp_add(float x) {
  int t = __builtin_amdgcn_update_dpp(0, __float_as_int(x), CTRL, 0xF, 0xF, true);
  return x + __int_as_float(t);
}
// full 16-lane sum (all 16 lanes of the row get the total)
__device__ __forceinline__ float r16sum(float x) {
  x = dpp_add<0xB1>(x);    // quad_perm xor1
  x = dpp_add<0x4E>(x);    // quad_perm xor2
  x = dpp_add<0x124>(x);   // row_ror:4
  x = dpp_add<0x128>(x);   // row_ror:8
  return x;
}

// ---------------------------------------------------------------------------
// Kernel 1 (unchanged): fcomb precompute + weight-GRN/softmax.
// ---------------------------------------------------------------------------
__global__ __launch_bounds__(256) void k_pw(
    const float* __restrict__ x,
    const float* __restrict__ fw2, const float* __restrict__ fb2,
    const float* __restrict__ fglu_w, const float* __restrict__ fglu_b,
    const float* __restrict__ ww1, const float* __restrict__ wb1,
    const float* __restrict__ ww2, const float* __restrict__ wb2,
    const float* __restrict__ wglu_w, const float* __restrict__ wglu_b,
    const float* __restrict__ wln_g, const float* __restrict__ wln_b,
    unsigned short* __restrict__ bfrag, float* __restrict__ bcomb,
    float* __restrict__ wout)
{
  __shared__ __align__(16) float smem[4096];
  const int tid = threadIdx.x;

  if (blockIdx.x < 128) {
    const int f  = blockIdx.x >> 2;
    const int ks = blockIdx.x & 3;
    const float* src = fw2 + ((size_t)f * 128 + ks * 32) * 128;
    for (int i = 0; i < 4; ++i) {
      int vi = tid + i * 256;
      *(float4v*)&smem[vi * 4] = *(const float4v*)&src[vi * 4];
    }
    __syncthreads();

    const int o2 = tid;
    float acc[32];
#pragma unroll
    for (int kk = 0; kk < 32; ++kk) acc[kk] = 0.f;
    float bacc = 0.f;

    for (int o = 0; o < 128; o += 4) {
      float gv0 = fglu_w[((size_t)f * 128 + o + 0) * 256 + o2];
      float gv1 = fglu_w[((size_t)f * 128 + o + 1) * 256 + o2];
      float gv2 = fglu_w[((size_t)f * 128 + o + 2) * 256 + o2];
      float gv3 = fglu_w[((size_t)f * 128 + o + 3) * 256 + o2];
      bacc += fb2[f * 128 + o + 0] * gv0 + fb2[f * 128 + o + 1] * gv1
            + fb2[f * 128 + o + 2] * gv2 + fb2[f * 128 + o + 3] * gv3;
#pragma unroll
      for (int kk = 0; kk < 32; ++kk) {
        float4v a4 = *(const float4v*)&smem[kk * 128 + o];
        acc[kk] += a4[0] * gv0 + a4[1] * gv1 + a4[2] * gv2 + a4[3] * gv3;
      }
    }

    const int type = o2 >> 7;
    const int hq   = o2 & 127;
    const int wv   = hq >> 5;
    const int hp   = (hq >> 4) & 1;
    const int cc   = hq & 15;
    const int ct   = wv * 4 + hp * 2 + type;

#pragma unroll
    for (int gg = 0; gg < 4; ++gg) {
      uint4v pk;
      unsigned int u0 = f2bf(acc[gg * 8 + 0]), u1 = f2bf(acc[gg * 8 + 1]);
      unsigned int u2 = f2bf(acc[gg * 8 + 2]), u3 = f2bf(acc[gg * 8 + 3]);
      unsigned int u4 = f2bf(acc[gg * 8 + 4]), u5 = f2bf(acc[gg * 8 + 5]);
      unsigned int u6 = f2bf(acc[gg * 8 + 6]), u7 = f2bf(acc[gg * 8 + 7]);
      pk[0] = u0 | (u1 << 16);
      pk[1] = u2 | (u3 << 16);
      pk[2] = u4 | (u5 << 16);
      pk[3] = u6 | (u7 << 16);
      size_t off = ((((size_t)f * 16 + ct) * 4 + ks) * 64 + (gg * 16 + cc)) * 8;
      *(uint4v*)(bfrag + off) = pk;
    }
    if (ks == 0)
      bcomb[f * 256 + ct * 16 + cc] = bacc + fglu_b[f * 256 + o2];

  } else {
    const int bid = blockIdx.x - 128;
    const int wv  = tid >> 6;
    const int l   = tid & 63;
    const int t   = bid * 4 + wv;
    float* S = smem + wv * 256;

    float xv = x[(size_t)t * 32 + (l & 31)];
    if (l < 32) S[l] = xv;
    float a0 = wb1[l], a1 = wb1[l + 64];
    __syncthreads();
    for (int f2 = 0; f2 < 32; ++f2) {
      float xf = S[f2];
      a0 = fmaf(xf, ww1[f2 * 128 + l], a0);
      a1 = fmaf(xf, ww1[f2 * 128 + l + 64], a1);
    }
    a0 = elu_f(a0); a1 = elu_f(a1);
    S[32 + l] = a0; S[32 + l + 64] = a1;
    __syncthreads();

    const int o    = l & 31;
    const int half = l >> 5;
    float b = 0.f;
    for (int hh = 0; hh < 64; ++hh)
      b = fmaf(S[32 + half * 64 + hh], ww2[(half * 64 + hh) * 32 + o], b);
    b += __shfl_xor(b, 32);
    b += wb2[o];
    S[160 + o] = b;
    __syncthreads();

    float g = wglu_b[l];
    for (int o2i = 0; o2i < 32; ++o2i)
      g = fmaf(S[160 + o2i], wglu_w[o2i * 64 + l], g);

    float gate = __shfl_xor(g, 32);
    float y = g * sigm_f(gate) + xv;
    float s = y;
    s += __shfl_xor(s, 1); s += __shfl_xor(s, 2); s += __shfl_xor(s, 4);
    s += __shfl_xor(s, 8); s += __shfl_xor(s, 16);
    float mean = s * (1.f / 32.f);
    float d = y - mean;
    float ss = d * d;
    ss += __shfl_xor(ss, 1); ss += __shfl_xor(ss, 2); ss += __shfl_xor(ss, 4);
    ss += __shfl_xor(ss, 8); ss += __shfl_xor(ss, 16);
    float rstd = rsqrtf(ss * (1.f / 32.f) + 1e-5f);
    const int cc = l & 31;
    float ln = d * rstd * wln_g[cc] + wln_b[cc];
    float mx = ln;
    mx = fmaxf(mx, __shfl_xor(mx, 1));  mx = fmaxf(mx, __shfl_xor(mx, 2));
    mx = fmaxf(mx, __shfl_xor(mx, 4));  mx = fmaxf(mx, __shfl_xor(mx, 8));
    mx = fmaxf(mx, __shfl_xor(mx, 16));
    float e = __expf(ln - mx);
    float se = e;
    se += __shfl_xor(se, 1); se += __shfl_xor(se, 2); se += __shfl_xor(se, 4);
    se += __shfl_xor(se, 8); se += __shfl_xor(se, 16);
    if (l < 32) wout[(size_t)t * 32 + l] = e / se;
  }
}

// ---------------------------------------------------------------------------
// Kernel 2 v4: R2 structure (2 barriers/feature, no cross-barrier prefetch —
// R3's prefetch caused scratch spills, 416 MB WRITE_SIZE) with:
//  - TOKB=16 -> 1024 blocks = 4 blocks/CU = 32 waves/CU resident
//  - __launch_bounds__(512,8) caps VGPR at 64 (R2 used 48; per-thread state
//    halved here, so no spill risk)
//  - v_cvt_pk_bf16_f32 staging pack
//  - LN atomics split across lanes c==0 (sum) / c==1 (sum-of-squares)
// Wave w owns (v,gate) ct-pair for h in [ (w>>1)*32+(w&1)*16, +16 ).
// Per wave per feature: 8 MFMA (2ct x 1rt x 4ks).
// ---------------------------------------------------------------------------
__global__ __launch_bounds__(512, 8) void k_main(
    const float* __restrict__ x,
    const float* __restrict__ fw1, const float* __restrict__ fb1,
    const float* __restrict__ fskip, const float* __restrict__ flng,
    const float* __restrict__ flnb,
    const unsigned short* __restrict__ bfrag, const float* __restrict__ bcomb,
    const float* __restrict__ wts, float* __restrict__ out)
{
  __shared__ __align__(16) unsigned short a_lds[TOKB * 128];  // 4 KB swizzled bf16
  __shared__ __align__(16) float x_lds[FDIM * TOKB];          // [f][t] 2 KB
  __shared__ __align__(16) float w_lds[FDIM * TOKB];          // [f][t] 2 KB
  __shared__ __align__(16) float sred[2][2][TOKB];            // [buf][{s,ss}][row]

  const int tid = threadIdx.x;
  const int w   = tid >> 6;
  const int l   = tid & 63;
  const int c   = l & 15;
  const int g16 = l >> 4;
  const int t0  = blockIdx.x * TOKB;
  const int hb  = (w >> 1) * 32 + (w & 1) * 16;   // h-col base for this wave
  const int ctb = (w >> 1) * 4 + (w & 1) * 2;     // ct' base (v at +0, gate +1)

  // stage x and weights tiles, transposed to [f][t]; zero both sred buffers
  {
    float xv = x[(size_t)t0 * FDIM + tid];
    float wv = wts[(size_t)t0 * FDIM + tid];
    int tt = tid >> 5, ff = tid & 31;
    x_lds[ff * TOKB + tt] = xv;
    w_lds[ff * TOKB + tt] = wv;
    if (tid < 64) ((float*)sred)[tid] = 0.f;
  }

  float out_acc[4];
#pragma unroll
  for (int i = 0; i < 4; ++i) out_acc[i] = 0.f;

  __syncthreads();

#pragma unroll 1
  for (int f = 0; f < FDIM; ++f) {
    // ---- h1 = ELU(x_f * fw1 + fb1) -> a_lds (bf16, XOR-swizzled) ----
    {
      int st = tid >> 5;            // row (token) 0..15
      int sk = (tid & 31) * 4;      // col 0..124
      float xf = x_lds[f * TOKB + st];
      float4v w1 = *(const float4v*)(fw1 + f * HDIM + sk);
      float4v b1 = *(const float4v*)(fb1 + f * HDIM + sk);
      uint2v pk;
      pk[0] = cvtpk(elu_f(fmaf(xf, w1[0], b1[0])),
                    elu_f(fmaf(xf, w1[1], b1[1])));
      pk[1] = cvtpk(elu_f(fmaf(xf, w1[2], b1[2])),
                    elu_f(fmaf(xf, w1[3], b1[3])));
      int byte = st * 256 + sk * 2;
      byte ^= (st & 7) << 4;
      *(uint2v*)((char*)a_lds + byte) = pk;
    }

    // ---- B fragments + per-feature scalars (issue before barrier) ----
    short8 bfr[2][4];
    {
      const unsigned short* bb = bfrag + (size_t)(f * 16 + ctb) * 2048;
#pragma unroll
      for (int ct2 = 0; ct2 < 2; ++ct2)
#pragma unroll
        for (int ks = 0; ks < 4; ++ks)
          bfr[ct2][ks] = *(const short8*)(bb + ct2 * 2048 + ks * 512 + l * 8);
    }
    float bc0 = bcomb[f * 256 + ctb * 16 + c];
    float bc1 = bcomb[f * 256 + (ctb + 1) * 16 + c];
    const int hcol = hb + c;
    float fsk = fskip[f * HDIM + hcol];
    float lgm = flng[f * HDIM + hcol];
    float lbt = flnb[f * HDIM + hcol];

    __syncthreads();   // B1: a_lds ready

    // ---- GEMM: 8 MFMA per wave ----
    float4v acc0 = (float4v){0.f, 0.f, 0.f, 0.f};
    float4v acc1 = (float4v){0.f, 0.f, 0.f, 0.f};
#pragma unroll
    for (int ks = 0; ks < 4; ++ks) {
      int byte = c * 256 + (ks * 32 + g16 * 8) * 2;
      byte ^= (c & 7) << 4;
      short8 afr = *(const short8*)((const char*)a_lds + byte);
      acc0 = __builtin_amdgcn_mfma_f32_16x16x32_bf16(afr, bfr[0][ks], acc0, 0, 0, 0);
      acc1 = __builtin_amdgcn_mfma_f32_16x16x32_bf16(afr, bfr[1][ks], acc1, 0, 0, 0);
    }

    // ---- epilogue: GLU + skip, DPP 16-lane LN partials, split atomics ----
    const int cb = f & 1, nb = cb ^ 1;
    float yv[4], red[4];
    {
      float4v x4 = *(const float4v*)&x_lds[f * TOKB + g16 * 4];
#pragma unroll
      for (int i = 0; i < 4; ++i) {
        float v0 = acc0[i] + bc0;
        float g0 = acc1[i] + bc1;
        float y  = fmaf(x4[i], fsk, v0 * sigm_f(g0));
        yv[i] = y;
        // lane c==0 accumulates sum, lane c==1 sum-of-squares; others idle late
        red[i] = r16sum(c == 1 ? y * y : y);   // need both: compute both sums
      }
      // r16sum gives every lane the full 16-lane sum of its own argument; but
      // we need sum(y) and sum(y^2) separately -> compute the second reduction
      // only for what lane 1 contributes is wrong. Do both properly:
    }
    // NOTE: red[] above holds sum(y) on even-c lanes' view only if all lanes
    // passed y. To keep it correct we recompute: all lanes pass y to one
    // r16sum and y*y to another (as in R2).
    float sv[4], ssv[4];
#pragma unroll
    for (int i = 0; i < 4; ++i) {
      sv[i]  = red[i];               // placeholder, overwritten below
    }
#pragma unroll
    for (int i = 0; i < 4; ++i) {
      sv[i]  = r16sum(yv[i]);
      ssv[i] = r16sum(yv[i] * yv[i]);
    }
    if (c < 2) {
#pragma unroll
      for (int i = 0; i < 4; ++i)
        atomicAdd(&sred[cb][c][g16 * 4 + i], c ? ssv[i] : sv[i]);
    }
    if (tid < 32) sred[nb][tid >> 4][tid & 15] = 0.f;   // zero next buffer

    __syncthreads();   // B2: sred[cb] complete

    // ---- LN finalize + weighted accumulate ----
    {
      float4v s4  = *(const float4v*)&sred[cb][0][g16 * 4];
      float4v ss4 = *(const float4v*)&sred[cb][1][g16 * 4];
      float4v w4  = *(const float4v*)&w_lds[f * TOKB + g16 * 4];
#pragma unroll
      for (int i = 0; i < 4; ++i) {
        float mean = s4[i] * (1.f / 128.f);
        float var  = ss4[i] * (1.f / 128.f) - mean * mean;
        float rstd = rsqrtf(var + 1e-5f);
        float o2 = (yv[i] - mean) * rstd * lgm + lbt;
        out_acc[i] = fmaf(w4[i], o2, out_acc[i]);
      }
    }
  }

  // ---- store ----
#pragma unroll
  for (int i = 0; i < 4; ++i) {
    int row = t0 + g16 * 4 + i;
    out[(size_t)row * HDIM + hb + c] = out_acc[i];
  }
}

extern "C" void kernel_launch(void* const* d_in, const int* in_sizes, int n_in,
                              void* d_out, int out_size, void* d_ws, size_t ws_size,
                              hipStream_t stream) {
  const float* x      = (const float*)d_in[0];
  const float* fw1    = (const float*)d_in[1];
  const float* fb1    = (const float*)d_in[2];
  const float* fw2    = (const float*)d_in[3];
  const float* fb2    = (const float*)d_in[4];
  const float* fglu_w = (const float*)d_in[5];
  const float* fglu_b = (const float*)d_in[6];
  const float* fskip  = (const float*)d_in[7];
  const float* fln_g  = (const float*)d_in[8];
  const float* fln_b  = (const float*)d_in[9];
  const float* ww1    = (const float*)d_in[10];
  const float* wb1    = (const float*)d_in[11];
  const float* ww2    = (const float*)d_in[12];
  const float* wb2    = (const float*)d_in[13];
  const float* wglu_w = (const float*)d_in[14];
  const float* wglu_b = (const float*)d_in[15];
  const float* wln_g  = (const float*)d_in[16];
  const float* wln_b  = (const float*)d_in[17];

  float* outp = (float*)d_out;
  float* wout = outp + (size_t)NTOK * HDIM;

  unsigned short* bfrag = (unsigned short*)d_ws;                  // 2 MiB bf16
  float* bcomb = (float*)((char*)d_ws + (size_t)2 * 1024 * 1024); // 32 KiB f32

  k_pw<<<dim3(128 + NTOK / 4), dim3(256), 0, stream>>>(
      x, fw2, fb2, fglu_w, fglu_b, ww1, wb1, ww2, wb2,
      wglu_w, wglu_b, wln_g, wln_b, bfrag, bcomb, wout);
  k_main<<<dim3(NTOK / TOKB), dim3(512), 0, stream>>>(
      x, fw1, fb1, fskip, fln_g, fln_b, bfrag, bcomb, wout, outp);
}

// Round 5
// 156.509 us; speedup vs baseline: 1.6178x; 1.2257x over previous
//
#include <hip/hip_runtime.h>
#include <cstdint>
#include <cstddef>

#define NTOK 16384
#define FDIM 32
#define HDIM 128
#define TOKB 32

typedef __attribute__((ext_vector_type(8))) short short8;     // bf16x8 MFMA frag
typedef __attribute__((ext_vector_type(4))) float float4v;
typedef __attribute__((ext_vector_type(2))) float float2v;
typedef __attribute__((ext_vector_type(4))) unsigned int uint4v;

__device__ __forceinline__ float elu_f(float x)  { return x > 0.f ? x : __expf(x) - 1.f; }
__device__ __forceinline__ float sigm_f(float x) { return 1.f / (1.f + __expf(-x)); }

// fp32 -> bf16 RNE (k_pw cold path)
__device__ __forceinline__ unsigned int f2bf(float f) {
  unsigned int u = __float_as_uint(f);
  u += 0x7FFFu + ((u >> 16) & 1u);
  return u >> 16;
}
// packed fp32x2 -> bf16x2 in one VALU op (RNE)
__device__ __forceinline__ unsigned int cvtpk(float lo, float hi) {
  unsigned int r;
  asm("v_cvt_pk_bf16_f32 %0, %1, %2" : "=v"(r) : "v"(lo), "v"(hi));
  return r;
}

// ---------------------------------------------------------------------------
// Kernel 1: (a) blocks [0,128): fcomb = fw2 @ fglu_w packed as MFMA
//     A-fragments (A = fcomb^T: 256 g-rows x 128 k). Tile order:
//     [f][w=h>>4][type=v/gate][ks][l*8+j], lane map row=l&15, k=8*(l>>4)+j.
//     bcomb stays in plain o2 = type*128+h order.
// (b) blocks [128,...): weight-GRN + softmax, one token per wave (unchanged).
// ---------------------------------------------------------------------------
__global__ __launch_bounds__(256) void k_pw(
    const float* __restrict__ x,
    const float* __restrict__ fw2, const float* __restrict__ fb2,
    const float* __restrict__ fglu_w, const float* __restrict__ fglu_b,
    const float* __restrict__ ww1, const float* __restrict__ wb1,
    const float* __restrict__ ww2, const float* __restrict__ wb2,
    const float* __restrict__ wglu_w, const float* __restrict__ wglu_b,
    const float* __restrict__ wln_g, const float* __restrict__ wln_b,
    unsigned short* __restrict__ bfrag, float* __restrict__ bcomb,
    float* __restrict__ wout)
{
  __shared__ __align__(16) float smem[4096];
  const int tid = threadIdx.x;

  if (blockIdx.x < 128) {
    const int f  = blockIdx.x >> 2;
    const int ks = blockIdx.x & 3;
    const float* src = fw2 + ((size_t)f * 128 + ks * 32) * 128;
    for (int i = 0; i < 4; ++i) {
      int vi = tid + i * 256;
      *(float4v*)&smem[vi * 4] = *(const float4v*)&src[vi * 4];
    }
    __syncthreads();

    const int o2 = tid;
    float acc[32];
#pragma unroll
    for (int kk = 0; kk < 32; ++kk) acc[kk] = 0.f;
    float bacc = 0.f;

    for (int o = 0; o < 128; o += 4) {
      float gv0 = fglu_w[((size_t)f * 128 + o + 0) * 256 + o2];
      float gv1 = fglu_w[((size_t)f * 128 + o + 1) * 256 + o2];
      float gv2 = fglu_w[((size_t)f * 128 + o + 2) * 256 + o2];
      float gv3 = fglu_w[((size_t)f * 128 + o + 3) * 256 + o2];
      bacc += fb2[f * 128 + o + 0] * gv0 + fb2[f * 128 + o + 1] * gv1
            + fb2[f * 128 + o + 2] * gv2 + fb2[f * 128 + o + 3] * gv3;
#pragma unroll
      for (int kk = 0; kk < 32; ++kk) {
        float4v a4 = *(const float4v*)&smem[kk * 128 + o];
        acc[kk] += a4[0] * gv0 + a4[1] * gv1 + a4[2] * gv2 + a4[3] * gv3;
      }
    }

    // pack as A-fragment: tile (f, w2=h>>4, type, ks); elem (l = r + gg*16, j)
    const int type = o2 >> 7;
    const int h    = o2 & 127;
    const int w2   = h >> 4;
    const int r    = h & 15;
    const size_t tbase = ((((size_t)f * 8 + w2) * 2 + type) * 4 + ks) * 512;
#pragma unroll
    for (int gg = 0; gg < 4; ++gg) {
      uint4v pk;
      pk[0] = f2bf(acc[gg * 8 + 0]) | (f2bf(acc[gg * 8 + 1]) << 16);
      pk[1] = f2bf(acc[gg * 8 + 2]) | (f2bf(acc[gg * 8 + 3]) << 16);
      pk[2] = f2bf(acc[gg * 8 + 4]) | (f2bf(acc[gg * 8 + 5]) << 16);
      pk[3] = f2bf(acc[gg * 8 + 6]) | (f2bf(acc[gg * 8 + 7]) << 16);
      *(uint4v*)(bfrag + tbase + (size_t)(r + gg * 16) * 8) = pk;
    }
    if (ks == 0)
      bcomb[f * 256 + o2] = bacc + fglu_b[f * 256 + o2];

  } else {
    const int bid = blockIdx.x - 128;
    const int wv  = tid >> 6;
    const int l   = tid & 63;
    const int t   = bid * 4 + wv;
    float* S = smem + wv * 256;

    float xv = x[(size_t)t * 32 + (l & 31)];
    if (l < 32) S[l] = xv;
    float a0 = wb1[l], a1 = wb1[l + 64];
    __syncthreads();
    for (int f2 = 0; f2 < 32; ++f2) {
      float xf = S[f2];
      a0 = fmaf(xf, ww1[f2 * 128 + l], a0);
      a1 = fmaf(xf, ww1[f2 * 128 + l + 64], a1);
    }
    a0 = elu_f(a0); a1 = elu_f(a1);
    S[32 + l] = a0; S[32 + l + 64] = a1;
    __syncthreads();

    const int o    = l & 31;
    const int half = l >> 5;
    float b = 0.f;
    for (int hh = 0; hh < 64; ++hh)
      b = fmaf(S[32 + half * 64 + hh], ww2[(half * 64 + hh) * 32 + o], b);
    b += __shfl_xor(b, 32);
    b += wb2[o];
    S[160 + o] = b;
    __syncthreads();

    float g = wglu_b[l];
    for (int o2i = 0; o2i < 32; ++o2i)
      g = fmaf(S[160 + o2i], wglu_w[o2i * 64 + l], g);

    float gate = __shfl_xor(g, 32);
    float y = g * sigm_f(gate) + xv;
    float s = y;
    s += __shfl_xor(s, 1); s += __shfl_xor(s, 2); s += __shfl_xor(s, 4);
    s += __shfl_xor(s, 8); s += __shfl_xor(s, 16);
    float mean = s * (1.f / 32.f);
    float d = y - mean;
    float ss = d * d;
    ss += __shfl_xor(ss, 1); ss += __shfl_xor(ss, 2); ss += __shfl_xor(ss, 4);
    ss += __shfl_xor(ss, 8); ss += __shfl_xor(ss, 16);
    float rstd = rsqrtf(ss * (1.f / 32.f) + 1e-5f);
    const int cc = l & 31;
    float ln = d * rstd * wln_g[cc] + wln_b[cc];
    float mx = ln;
    mx = fmaxf(mx, __shfl_xor(mx, 1));  mx = fmaxf(mx, __shfl_xor(mx, 2));
    mx = fmaxf(mx, __shfl_xor(mx, 4));  mx = fmaxf(mx, __shfl_xor(mx, 8));
    mx = fmaxf(mx, __shfl_xor(mx, 16));
    float e = __expf(ln - mx);
    float se = e;
    se += __shfl_xor(se, 1); se += __shfl_xor(se, 2); se += __shfl_xor(se, 4);
    se += __shfl_xor(se, 8); se += __shfl_xor(se, 16);
    if (l < 32) wout[(size_t)t * 32 + l] = e / se;
  }
}

// ---------------------------------------------------------------------------
// Kernel 2 v5: TRANSPOSED GEMM orientation.
//   A = fcomb^T (g-rows), B = h1^T (k x tokens) from LDS.
//   C: g-row = (l>>4)*4+i, token = l&15. Wave w owns h in [w*16, w*16+16)
//   (v-tile + gate-tile) for 32 tokens (2 token-tiles).
//   Per lane: 4 contiguous h x 2 tokens; v/gate of same h in same lane/reg.
//   LN: 3 in-lane adds + shfl_xor(16,32) + 1 atomic lane-set per stat.
//   2 barriers/feature (R2-validated structure), TOKB=32, 512 blocks.
// ---------------------------------------------------------------------------
__global__ __launch_bounds__(512, 4) void k_main(
    const float* __restrict__ x,
    const float* __restrict__ fw1, const float* __restrict__ fb1,
    const float* __restrict__ fskip, const float* __restrict__ flng,
    const float* __restrict__ flnb,
    const unsigned short* __restrict__ bfrag, const float* __restrict__ bcomb,
    const float* __restrict__ wts, float* __restrict__ out)
{
  __shared__ __align__(16) unsigned short a_lds[TOKB * 128];  // 8 KB h1, swizzled
  __shared__ __align__(16) float x_lds[FDIM * TOKB];          // [f][t] 4 KB
  __shared__ __align__(16) float w_lds[FDIM * TOKB];          // [f][t] 4 KB
  __shared__ __align__(16) float sred[2][2][TOKB];            // [buf][{s,ss}][tok]

  const int tid = threadIdx.x;
  const int w   = tid >> 6;
  const int l   = tid & 63;
  const int tk  = l & 15;        // token within a 16-token tile
  const int rg  = l >> 4;        // row-group: lane's 4 h's = h0..h0+3
  const int t0  = blockIdx.x * TOKB;
  const int h0  = w * 16 + rg * 4;

  // stage x and weights tiles, transposed to [f][t]; zero sred buf 0
  {
    float2v xv = *(const float2v*)(x   + (size_t)t0 * FDIM + tid * 2);
    float2v wv = *(const float2v*)(wts + (size_t)t0 * FDIM + tid * 2);
#pragma unroll
    for (int e = 0; e < 2; ++e) {
      int flat = tid * 2 + e;
      int tt = flat >> 5, ff = flat & 31;
      x_lds[ff * TOKB + tt] = xv[e];
      w_lds[ff * TOKB + tt] = wv[e];
    }
    if (tid < 64) ((float*)sred)[tid] = 0.f;
  }

  float4v oa0 = (float4v){0.f, 0.f, 0.f, 0.f};
  float4v oa1 = (float4v){0.f, 0.f, 0.f, 0.f};

  __syncthreads();

#pragma unroll 1
  for (int f = 0; f < FDIM; ++f) {
    // ---- stage h1 = ELU(x_f*fw1+fb1) -> a_lds[token][k] bf16, XOR-swizzled ----
    {
      int st = tid >> 4;            // token 0..31
      int sk = (tid & 15) * 8;      // k 0..120
      float xf = x_lds[f * TOKB + st];
      float4v w1a = *(const float4v*)(fw1 + f * HDIM + sk);
      float4v w1b = *(const float4v*)(fw1 + f * HDIM + sk + 4);
      float4v b1a = *(const float4v*)(fb1 + f * HDIM + sk);
      float4v b1b = *(const float4v*)(fb1 + f * HDIM + sk + 4);
      uint4v pk;
      pk[0] = cvtpk(elu_f(fmaf(xf, w1a[0], b1a[0])),
                    elu_f(fmaf(xf, w1a[1], b1a[1])));
      pk[1] = cvtpk(elu_f(fmaf(xf, w1a[2], b1a[2])),
                    elu_f(fmaf(xf, w1a[3], b1a[3])));
      pk[2] = cvtpk(elu_f(fmaf(xf, w1b[0], b1b[0])),
                    elu_f(fmaf(xf, w1b[1], b1b[1])));
      pk[3] = cvtpk(elu_f(fmaf(xf, w1b[2], b1b[2])),
                    elu_f(fmaf(xf, w1b[3], b1b[3])));
      int sb = st * 256 + sk * 2;
      sb ^= (st & 7) << 4;
      *(uint4v*)((char*)a_lds + sb) = pk;
    }

    // ---- A-frags (fcomb, L2-resident) + per-feature scalars ----
    short8 aV[4], aG[4];
    {
      const unsigned short* bb = bfrag + (((size_t)f * 8 + w) * 8) * 512 + (size_t)l * 8;
#pragma unroll
      for (int ks = 0; ks < 4; ++ks) {
        aV[ks] = *(const short8*)(bb + (size_t)ks * 512);
        aG[ks] = *(const short8*)(bb + (size_t)(4 + ks) * 512);
      }
    }
    float4v bcv = *(const float4v*)(bcomb + f * 256 + h0);
    float4v bcg = *(const float4v*)(bcomb + f * 256 + 128 + h0);
    float4v fs4 = *(const float4v*)(fskip + f * HDIM + h0);
    float4v lg4 = *(const float4v*)(flng  + f * HDIM + h0);
    float4v lb4 = *(const float4v*)(flnb  + f * HDIM + h0);
    float xt0 = x_lds[f * TOKB + tk],      wt0 = w_lds[f * TOKB + tk];
    float xt1 = x_lds[f * TOKB + 16 + tk], wt1 = w_lds[f * TOKB + 16 + tk];

    __syncthreads();   // B1: a_lds ready

    // ---- GEMM: 16 MFMA per wave ----
    float4v av0 = (float4v){0.f,0.f,0.f,0.f}, ag0 = av0, av1 = av0, ag1 = av0;
#pragma unroll
    for (int ks = 0; ks < 4; ++ks) {
      int b0 = tk * 256 + (ks * 32 + rg * 8) * 2;
      b0 ^= (tk & 7) << 4;
      short8 hf0 = *(const short8*)((const char*)a_lds + b0);
      int b1 = (16 + tk) * 256 + (ks * 32 + rg * 8) * 2;
      b1 ^= (tk & 7) << 4;
      short8 hf1 = *(const short8*)((const char*)a_lds + b1);
      av0 = __builtin_amdgcn_mfma_f32_16x16x32_bf16(aV[ks], hf0, av0, 0, 0, 0);
      ag0 = __builtin_amdgcn_mfma_f32_16x16x32_bf16(aG[ks], hf0, ag0, 0, 0, 0);
      av1 = __builtin_amdgcn_mfma_f32_16x16x32_bf16(aV[ks], hf1, av1, 0, 0, 0);
      ag1 = __builtin_amdgcn_mfma_f32_16x16x32_bf16(aG[ks], hf1, ag1, 0, 0, 0);
    }

    // ---- epilogue: GLU + skip; in-lane LN partials + 2-stage shfl ----
    const int cb = f & 1, nb = cb ^ 1;
    float4v y0, y1;
    float s0 = 0.f, ss0 = 0.f, s1 = 0.f, ss1 = 0.f;
#pragma unroll
    for (int i = 0; i < 4; ++i) {
      float ya = fmaf(xt0, fs4[i], (av0[i] + bcv[i]) * sigm_f(ag0[i] + bcg[i]));
      float yb = fmaf(xt1, fs4[i], (av1[i] + bcv[i]) * sigm_f(ag1[i] + bcg[i]));
      y0[i] = ya; y1[i] = yb;
      s0 += ya; ss0 = fmaf(ya, ya, ss0);
      s1 += yb; ss1 = fmaf(yb, yb, ss1);
    }
    s0  += __shfl_xor(s0, 16);  s0  += __shfl_xor(s0, 32);
    ss0 += __shfl_xor(ss0, 16); ss0 += __shfl_xor(ss0, 32);
    s1  += __shfl_xor(s1, 16);  s1  += __shfl_xor(s1, 32);
    ss1 += __shfl_xor(ss1, 16); ss1 += __shfl_xor(ss1, 32);
    if (rg == 0) {
      atomicAdd(&sred[cb][0][tk], s0);
      atomicAdd(&sred[cb][0][16 + tk], s1);
    } else if (rg == 1) {
      atomicAdd(&sred[cb][1][tk], ss0);
      atomicAdd(&sred[cb][1][16 + tk], ss1);
    }
    if (tid < 64) ((float*)(sred[nb]))[tid] = 0.f;   // zero next buffer

    __syncthreads();   // B2: sred[cb] complete

    // ---- LN finalize (2 tokens per lane) + weighted accumulate ----
    {
      float sA  = sred[cb][0][tk],      ssA = sred[cb][1][tk];
      float sB  = sred[cb][0][16 + tk], ssB = sred[cb][1][16 + tk];
      float m0 = sA * (1.f / 128.f);
      float m1 = sB * (1.f / 128.f);
      float v0 = fmaf(-m0, m0, ssA * (1.f / 128.f));
      float v1 = fmaf(-m1, m1, ssB * (1.f / 128.f));
      float rw0 = rsqrtf(v0 + 1e-5f) * wt0;
      float rw1 = rsqrtf(v1 + 1e-5f) * wt1;
#pragma unroll
      for (int i = 0; i < 4; ++i) {
        oa0[i] = fmaf((y0[i] - m0) * rw0, lg4[i], fmaf(wt0, lb4[i], oa0[i]));
        oa1[i] = fmaf((y1[i] - m1) * rw1, lg4[i], fmaf(wt1, lb4[i], oa1[i]));
      }
    }
  }

  // ---- store: per lane 2 x 16B contiguous ----
  *(float4v*)(out + (size_t)(t0 + tk) * HDIM + h0)      = oa0;
  *(float4v*)(out + (size_t)(t0 + 16 + tk) * HDIM + h0) = oa1;
}

extern "C" void kernel_launch(void* const* d_in, const int* in_sizes, int n_in,
                              void* d_out, int out_size, void* d_ws, size_t ws_size,
                              hipStream_t stream) {
  const float* x      = (const float*)d_in[0];
  const float* fw1    = (const float*)d_in[1];
  const float* fb1    = (const float*)d_in[2];
  const float* fw2    = (const float*)d_in[3];
  const float* fb2    = (const float*)d_in[4];
  const float* fglu_w = (const float*)d_in[5];
  const float* fglu_b = (const float*)d_in[6];
  const float* fskip  = (const float*)d_in[7];
  const float* fln_g  = (const float*)d_in[8];
  const float* fln_b  = (const float*)d_in[9];
  const float* ww1    = (const float*)d_in[10];
  const float* wb1    = (const float*)d_in[11];
  const float* ww2    = (const float*)d_in[12];
  const float* wb2    = (const float*)d_in[13];
  const float* wglu_w = (const float*)d_in[14];
  const float* wglu_b = (const float*)d_in[15];
  const float* wln_g  = (const float*)d_in[16];
  const float* wln_b  = (const float*)d_in[17];

  float* outp = (float*)d_out;
  float* wout = outp + (size_t)NTOK * HDIM;

  unsigned short* bfrag = (unsigned short*)d_ws;                  // 2 MiB bf16
  float* bcomb = (float*)((char*)d_ws + (size_t)2 * 1024 * 1024); // 32 KiB f32

  k_pw<<<dim3(128 + NTOK / 4), dim3(256), 0, stream>>>(
      x, fw2, fb2, fglu_w, fglu_b, ww1, wb1, ww2, wb2,
      wglu_w, wglu_b, wln_g, wln_b, bfrag, bcomb, wout);
  k_main<<<dim3(NTOK / TOKB), dim3(512), 0, stream>>>(
      x, fw1, fb1, fskip, fln_g, fln_b, bfrag, bcomb, wout, outp);
}